// Round 10
// baseline (190.449 us; speedup 1.0000x reference)
//
#include <hip/hip_runtime.h>
#include <hip/hip_bf16.h>
#include <math.h>

// Problem constants
#define B_   8
#define H_   8
#define S_   2048
#define D_   64      // head dim
#define BH_  64      // B*H
#define DPROJ_ 512

typedef __attribute__((ext_vector_type(8)))  _Float16 f16x8;
typedef __attribute__((ext_vector_type(2)))  _Float16 f16x2;
typedef __attribute__((ext_vector_type(4)))  float    f32x4;
typedef __attribute__((ext_vector_type(16))) float    f32x16;
typedef __attribute__((ext_vector_type(4)))  int      i32x4;

static __device__ __forceinline__ short f16bits(float f) {
    return __builtin_bit_cast(short, (_Float16)f);   // v_cvt_f16_f32 (RNE)
}

static __device__ __forceinline__ f16x8 load8_f32_f16(const float* p) {
    const float4 a = ((const float4*)p)[0];
    const float4 b = ((const float4*)p)[1];
    f16x8 r;
    r[0] = (_Float16)a.x; r[1] = (_Float16)a.y; r[2] = (_Float16)a.z; r[3] = (_Float16)a.w;
    r[4] = (_Float16)b.x; r[5] = (_Float16)b.y; r[6] = (_Float16)b.z; r[7] = (_Float16)b.w;
    return r;
}

// exp2: guarantee a single v_exp_f32 (HW computes 2^x)
#if __has_builtin(__builtin_amdgcn_exp2f)
#define EXP2(x) __builtin_amdgcn_exp2f(x)
#else
#define EXP2(x) exp2f(x)
#endif

// permlane32_swap: newA = {A_lo, B_lo}, newB = {A_hi, B_hi}.
static __device__ __forceinline__ void pl32swap(unsigned int& a, unsigned int& b) {
#if __has_builtin(__builtin_amdgcn_permlane32_swap)
    auto r = __builtin_amdgcn_permlane32_swap((int)a, (int)b, false, false);
    a = (unsigned int)r[0];
    b = (unsigned int)r[1];
#else
    const bool lh0 = ((threadIdx.x & 63) < 32);
    unsigned int xa = (unsigned int)__shfl_xor((int)a, 32);
    unsigned int xb = (unsigned int)__shfl_xor((int)b, 32);
    unsigned int na = lh0 ? a : xb;
    unsigned int nb = lh0 ? xa : b;
    a = na; b = nb;
#endif
}

// ---------------------------------------------------------------------------
// WORKSPACE LAYOUTS (fragment-major; unchanged from R12 — passed):
//   q_ws: [bh][s][64] f16, q pre-scaled by 0.1125*log2(e).
//   k_ws: [bh][T][h][lh][m32][8] f16  — wave reads frag h as one 1KB block.
//   v_ws: [bh][T][fg][lh][m32][8] f16 — same addressing structure.
// ---------------------------------------------------------------------------
#define QKST 520

__global__ __launch_bounds__(256)
void proj_kernel(const float* __restrict__ query, const float* __restrict__ key,
                 const float* __restrict__ value,
                 const float* __restrict__ Wq, const float* __restrict__ bq,
                 const float* __restrict__ Wk, const float* __restrict__ bk,
                 const float* __restrict__ Wv, const float* __restrict__ bv,
                 short* __restrict__ qws, short* __restrict__ kws,
                 short* __restrict__ vws)
{
    __shared__ __align__(16) short shbuf[16384];   // 32 KB, unioned per path

    const int tid  = threadIdx.x;
    const int wave = tid >> 6;
    const int lane = tid & 63;
    const int n    = lane & 15;
    const int quad = lane >> 4;
    const int kind = blockIdx.y;             // 0=q, 1=k, 2=v

    if (kind < 2) {
        short* tile = shbuf;                 // 16 x QKST = 16640 B
        const int r0   = blockIdx.x * 16;
        const int b    = r0 >> 11;
        const int s0   = r0 & 2047;
        // (1-dropout)/num_heads = 0.9/8 = 0.1125, times log2(e) for exp2 softmax
        const float QS = 0.16230319188537014f;

        const float* X    = kind ? key : query;
        const float* W    = kind ? Wk  : Wq;
        const float* bias = kind ? bk  : bq;
        short*       ows  = kind ? kws : qws;

        f16x8 af = load8_f32_f16(X + (r0 + n) * 32 + quad * 8);
        #pragma unroll
        for (int i = 0; i < 8; ++i) {
            const int c0 = wave * 128 + i * 16;
            f16x8 bfr = load8_f32_f16(W + (c0 + n) * 32 + quad * 8);
            f32x4 acc = {0.f, 0.f, 0.f, 0.f};
            acc = __builtin_amdgcn_mfma_f32_16x16x32_f16(af, bfr, acc, 0, 0, 0);
            const int c = c0 + n;
            const float bsf = bias[c];
            #pragma unroll
            for (int r = 0; r < 4; ++r) {
                float v = acc[r] + bsf;
                if (kind == 0) v *= QS;
                tile[(quad * 4 + r) * QKST + c] = f16bits(v);
            }
        }
        __syncthreads();

        #pragma unroll
        for (int k = 0; k < 4; ++k) {
            const int slot = k * 256 + tid;
            const int li   = slot & 7;          // d8 within head = h*2+lh
            const int chunk= slot >> 3;
            const int row  = chunk & 15;
            const int hd   = chunk >> 4;        // head 0..7
            uint4 vv = *(const uint4*)(tile + row * QKST + hd * 64 + li * 8);
            const int bh = b * 8 + hd;
            if (kind == 0) {
                *(uint4*)(ows + ((size_t)bh * S_ + s0 + row) * 64 + li * 8) = vv;
            } else {
                const int s = s0 + row;
                // k frag layout: bh*S*64 + T*2048 + li*256 + m32*8
                *(uint4*)(ows + (size_t)bh * (S_ * 64)
                              + (size_t)(s >> 5) * 2048 + li * 256 + (s & 31) * 8) = vv;
            }
        }
    } else {
        if (blockIdx.x >= 256) return;       // v path needs only 256 blocks
        short* vtile = shbuf;                // 2*256*32 shorts = 32768 B
        const int r0   = blockIdx.x * 64;
        const int b    = r0 >> 11;
        const int s0   = r0 & 2047;
        const int sub  = wave >> 1;
        const int sh   = (wave & 1) * 16;

        #pragma unroll
        for (int half = 0; half < 2; ++half) {
            const int cbh = half * 256;
            f16x8 bfr = load8_f32_f16(value + (r0 + sub * 32 + sh + n) * 32 + quad * 8);
            #pragma unroll
            for (int i = 0; i < 16; ++i) {
                const int c0 = cbh + i * 16;
                f16x8 af = load8_f32_f16(Wv + (c0 + n) * 32 + quad * 8);
                f32x4 acc = {0.f, 0.f, 0.f, 0.f};
                acc = __builtin_amdgcn_mfma_f32_16x16x32_f16(af, bfr, acc, 0, 0, 0);
                #pragma unroll
                for (int r = 0; r < 4; ++r) {
                    const int dc = c0 + quad * 4 + r;
                    float v = acc[r] + bv[dc];
                    vtile[(sub * 256 + (dc - cbh)) * 32 + sh + n] = f16bits(v);
                }
            }
            __syncthreads();

            #pragma unroll
            for (int k = 0; k < 8; ++k) {
                const int slot = k * 256 + tid;
                const int li   = slot & 3;          // k8 within tile (0..3)
                const int cl   = (slot >> 2) & 255;
                const int sb   = slot >> 10;
                const int c    = cbh + cl;
                const int bh   = b * 8 + (c >> 6);
                const int d    = c & 63;
                const int stile= (s0 >> 5) + sb;
                uint4 vv = *(const uint4*)(vtile + (sb * 256 + cl) * 32 + li * 8);
                // v frag layout: bh*S*64 + T*2048 + ((d>>5)*4+(li>>1)*2+(li&1))*256 + m32*8
                *(uint4*)(vws + (size_t)bh * (S_ * 64)
                              + (size_t)stile * 2048
                              + ((d >> 5) * 4 + (li >> 1) * 2 + (li & 1)) * 256
                              + (d & 31) * 8) = vv;
            }
            if (half == 0) __syncthreads();  // reuse vtile for second half
        }
    }
}

// ---------------------------------------------------------------------------
// Kernel 2: flash attention. R16 = R15 (80.4 us: no-LDS frag-major,
// A/B ping-pong, setprio) + intra-tile qg BRAID + fdot2 row-sums.
// Ledger: barriers free (R4), latency free (R5), LDS free (R6), occupancy
// hard-capped at 2 waves/SIMD (R7: 2048 waves total, 176-reg state),
// cross-tile 2-state pipeline negative (R8: AGPR thrash), setprio +2.7%
// (R9). Remaining gap = per-tile dependency chain exposed at 2 waves/SIMD.
// Braid: compute BOTH qg score matrices first (st[0],st[1] live, +16 VGPR,
// no AGPR moves — unlike R8's cross-tile attempt): the matrix pipe streams
// 8 MFMAs as two independent 4-chains, and qg1's exp can overlap qg0's PV.
// fdot2: row-sums from the packed f16 pairs (v_dot2_f32_f16) — fewer VALU
// ops than 15 f32 adds, numerics identical to what PV consumes.
// Pre-commit: flash >= 79.5 us or spill (WRITE >> 33MB) -> ROOFLINE.
// ---------------------------------------------------------------------------
#define OTS 36   // epilogue LDS row stride (f32) for one 32-wide d-tile

static __device__ __forceinline__ void flash_compute(
    const f16x8 (&kf)[4], const f16x8 (&va)[4],
    const f16x8 (&qb)[2][4], const f32x16& z16,
    f32x16 (&o)[2][2], float (&pl)[2])
{
    // Stage 1: BOTH qg score matrices — two independent 4-MFMA chains
    // stream the matrix pipe with no cross-qg dependency stalls.
    f32x16 st[2];
    __builtin_amdgcn_s_setprio(1);
    #pragma unroll
    for (int qg = 0; qg < 2; ++qg) {
        st[qg] = __builtin_amdgcn_mfma_f32_32x32x16_f16(kf[0], qb[qg][0], z16, 0, 0, 0);
        #pragma unroll
        for (int h = 1; h < 4; ++h)
            st[qg] = __builtin_amdgcn_mfma_f32_32x32x16_f16(kf[h], qb[qg][h], st[qg], 0, 0, 0);
    }
    __builtin_amdgcn_s_setprio(0);

    // Stage 2: finish qg0 then qg1 (qg1's exp overlaps qg0's PV in the
    // scheduler window; st[1] stays live — VGPR only, no accvgpr traffic).
    #pragma unroll
    for (int qg = 0; qg < 2; ++qg) {
        float p[16];
        #pragma unroll
        for (int r = 0; r < 16; ++r) p[r] = EXP2(st[qg][r]);

        unsigned int pk[8];
        #pragma unroll
        for (int i = 0; i < 8; ++i)
            pk[i] = __builtin_bit_cast(unsigned int,
                      __builtin_amdgcn_cvt_pkrtz(p[2 * i], p[2 * i + 1]));

        // row-sum of this lane's 16 p's, from the PRE-swap packed pairs.
#if __has_builtin(__builtin_amdgcn_fdot2)
        {
            const f16x2 one2 = {(_Float16)1.0f, (_Float16)1.0f};
            float sa = 0.f, sb = 0.f, sc = 0.f, sd = 0.f;
            sa = __builtin_amdgcn_fdot2(__builtin_bit_cast(f16x2, pk[0]), one2, sa, false);
            sa = __builtin_amdgcn_fdot2(__builtin_bit_cast(f16x2, pk[1]), one2, sa, false);
            sb = __builtin_amdgcn_fdot2(__builtin_bit_cast(f16x2, pk[2]), one2, sb, false);
            sb = __builtin_amdgcn_fdot2(__builtin_bit_cast(f16x2, pk[3]), one2, sb, false);
            sc = __builtin_amdgcn_fdot2(__builtin_bit_cast(f16x2, pk[4]), one2, sc, false);
            sc = __builtin_amdgcn_fdot2(__builtin_bit_cast(f16x2, pk[5]), one2, sc, false);
            sd = __builtin_amdgcn_fdot2(__builtin_bit_cast(f16x2, pk[6]), one2, sd, false);
            sd = __builtin_amdgcn_fdot2(__builtin_bit_cast(f16x2, pk[7]), one2, sd, false);
            pl[qg] += (sa + sb) + (sc + sd);
        }
#else
        {
            float s01 = (p[0]+p[1]) + (p[2]+p[3]);
            float s23 = (p[4]+p[5]) + (p[6]+p[7]);
            float s45 = (p[8]+p[9]) + (p[10]+p[11]);
            float s67 = (p[12]+p[13]) + (p[14]+p[15]);
            pl[qg] += (s01 + s23) + (s45 + s67);
        }
#endif

        pl32swap(pk[0], pk[2]);
        pl32swap(pk[1], pk[3]);
        pl32swap(pk[4], pk[6]);
        pl32swap(pk[5], pk[7]);

        i32x4 bi0, bi1;
        bi0[0] = (int)pk[0]; bi0[1] = (int)pk[1];
        bi0[2] = (int)pk[2]; bi0[3] = (int)pk[3];
        bi1[0] = (int)pk[4]; bi1[1] = (int)pk[5];
        bi1[2] = (int)pk[6]; bi1[3] = (int)pk[7];
        f16x8 bf0 = __builtin_bit_cast(f16x8, bi0);
        f16x8 bf1 = __builtin_bit_cast(f16x8, bi1);

        __builtin_amdgcn_s_setprio(1);
        #pragma unroll
        for (int t = 0; t < 2; ++t) {
            o[qg][t] = __builtin_amdgcn_mfma_f32_32x32x16_f16(va[t * 2 + 0], bf0, o[qg][t], 0, 0, 0);
            o[qg][t] = __builtin_amdgcn_mfma_f32_32x32x16_f16(va[t * 2 + 1], bf1, o[qg][t], 0, 0, 0);
        }
        __builtin_amdgcn_s_setprio(0);
    }
}

__global__ __launch_bounds__(256, 2)
void flash_kernel(const short* __restrict__ qws, const short* __restrict__ kws,
                  const short* __restrict__ vws, float* __restrict__ out)
{
    __shared__ __align__(16) float olds[4 * 32 * OTS];   // 18432 B (epilogue only)

    const int tid  = threadIdx.x;
    const int wave = tid >> 6;
    const int lane = tid & 63;
    const int m32  = lane & 31;
    const int lh   = lane >> 5;          // lane-half
    const int koff = lh * 8;
    const int bh   = blockIdx.x;                     // XCD = bh % 8
    const int q0   = blockIdx.y * 256 + wave * 64;   // 64 q-rows per wave

    const short* qbase = qws + (size_t)bh * S_ * D_;
    const short* kfb   = kws + (size_t)bh * (S_ * 64);   // frag-major tiles
    const short* vfb   = vws + (size_t)bh * (S_ * 64);
    const int loff = lh * 256 + m32 * 8;                 // lane part of frag addr

    // Q^T B-frags (held): qb[qg][h]: B[d=h*16+lh*8+j][q=m32]
    f16x8 qb[2][4];
    #pragma unroll
    for (int qg = 0; qg < 2; ++qg)
        #pragma unroll
        for (int h = 0; h < 4; ++h)
            qb[qg][h] = *(const f16x8*)(qbase + (q0 + qg * 32 + m32) * D_ + h * 16 + koff);

    f32x16 z16;
    #pragma unroll
    for (int r = 0; r < 16; ++r) z16[r] = 0.f;

    f32x16 o[2][2];      // [qg][d-tile] O^T accumulators
    float  pl[2] = {0.f, 0.f};
    #pragma unroll
    for (int qg = 0; qg < 2; ++qg)
        #pragma unroll
        for (int t = 0; t < 2; ++t)
            o[qg][t] = z16;

    // frag loads: 8 contiguous 1KB wave-loads per tile, direct from global
    #define LOADFRAGS(T, kf, va) do {                                        \
        const short* kp_ = kfb + (size_t)(T) * 2048 + loff;                  \
        const short* vp_ = vfb + (size_t)(T) * 2048 + loff;                  \
        kf[0] = *(const f16x8*)(kp_);                                        \
        kf[1] = *(const f16x8*)(kp_ + 512);                                  \
        kf[2] = *(const f16x8*)(kp_ + 1024);                                 \
        kf[3] = *(const f16x8*)(kp_ + 1536);                                 \
        va[0] = *(const f16x8*)(vp_);                                        \
        va[1] = *(const f16x8*)(vp_ + 512);                                  \
        va[2] = *(const f16x8*)(vp_ + 1024);                                 \
        va[3] = *(const f16x8*)(vp_ + 1536);                                 \
    } while (0)

    f16x8 kfA[4], vaA[4], kfB[4], vaB[4];
    LOADFRAGS(0, kfA, vaA);

    for (int it = 0; it < 64; it += 2) {
        LOADFRAGS(it + 1, kfB, vaB);             // it+1 <= 63 always
        flash_compute(kfA, vaA, qb, z16, o, pl);
        if (it + 2 < 64)
            LOADFRAGS(it + 2, kfA, vaA);
        flash_compute(kfB, vaB, qb, z16, o, pl);
    }
    #undef LOADFRAGS

    // epilogue: complete row sums across lane-halves, normalize, transpose
    // O^T -> O one 32-wide d-tile at a time through per-wave LDS (32x36 f32,
    // per-wave region — no cross-wave hazard, no barrier), coalesced stores.
    const int b = bh >> 3, h = bh & 7;
    float* ow = olds + wave * (32 * OTS);
    #pragma unroll
    for (int qg = 0; qg < 2; ++qg) {
        float rs = pl[qg] + __shfl_xor(pl[qg], 32);
        float rl = 1.0f / rs;
        #pragma unroll
        for (int t = 0; t < 2; ++t) {
            const f32x16& ot = o[qg][t];
            #pragma unroll
            for (int g = 0; g < 4; ++g) {
                f32x4 w;
                w[0] = ot[g * 4 + 0] * rl;
                w[1] = ot[g * 4 + 1] * rl;
                w[2] = ot[g * 4 + 2] * rl;
                w[3] = ot[g * 4 + 3] * rl;
                // element (q=m32, dcol=r+8g+4lh) of this 32-wide d-tile
                *(f32x4*)(ow + m32 * OTS + 8 * g + 4 * lh) = w;
            }
            #pragma unroll
            for (int c = 0; c < 4; ++c) {
                const int row = (lane >> 3) + 8 * c;       // q-row within 32-row group
                f32x4 v = *(const f32x4*)(ow + row * OTS + (lane & 7) * 4);
                const int sq = q0 + qg * 32 + row;
                *(f32x4*)(out + ((size_t)(b * S_ + sq)) * DPROJ_
                              + h * 64 + t * 32 + (lane & 7) * 4) = v;
            }
        }
    }
}

// ---------------------------------------------------------------------------
extern "C" void kernel_launch(void* const* d_in, const int* in_sizes, int n_in,
                              void* d_out, int out_size, void* d_ws, size_t ws_size,
                              hipStream_t stream)
{
    const float* query = (const float*)d_in[0];
    const float* key   = (const float*)d_in[1];
    const float* value = (const float*)d_in[2];
    // d_in[3] = mask (int32) -- only its shape feeds the reference; unused.
    const float* Wq = (const float*)d_in[4];
    const float* bq = (const float*)d_in[5];
    const float* Wk = (const float*)d_in[6];
    const float* bk = (const float*)d_in[7];
    const float* Wv = (const float*)d_in[8];
    const float* bv = (const float*)d_in[9];

    float* out = (float*)d_out;
    short* ws  = (short*)d_ws;
    const size_t TSZ = (size_t)BH_ * S_ * D_;
    short* qws = ws;
    short* kws = ws + TSZ;
    short* vws = ws + 2 * TSZ;

    proj_kernel<<<dim3((B_ * S_) / 16, 3), 256, 0, stream>>>(
        query, key, value, Wq, bq, Wk, bk, Wv, bv, qws, kws, vws);
    flash_kernel<<<dim3(BH_, S_ / 256), 256, 0, stream>>>(qws, kws, vws, out);
}

// Round 11
// 186.366 us; speedup vs baseline: 1.0219x; 1.0219x over previous
//
#include <hip/hip_runtime.h>
#include <hip/hip_bf16.h>
#include <math.h>

// Problem constants
#define B_   8
#define H_   8
#define S_   2048
#define D_   64      // head dim
#define BH_  64      // B*H
#define DPROJ_ 512

typedef __attribute__((ext_vector_type(8)))  _Float16 f16x8;
typedef __attribute__((ext_vector_type(4)))  float    f32x4;
typedef __attribute__((ext_vector_type(16))) float    f32x16;
typedef __attribute__((ext_vector_type(4)))  int      i32x4;

static __device__ __forceinline__ short f16bits(float f) {
    return __builtin_bit_cast(short, (_Float16)f);   // v_cvt_f16_f32 (RNE)
}

static __device__ __forceinline__ f16x8 load8_f32_f16(const float* p) {
    const float4 a = ((const float4*)p)[0];
    const float4 b = ((const float4*)p)[1];
    f16x8 r;
    r[0] = (_Float16)a.x; r[1] = (_Float16)a.y; r[2] = (_Float16)a.z; r[3] = (_Float16)a.w;
    r[4] = (_Float16)b.x; r[5] = (_Float16)b.y; r[6] = (_Float16)b.z; r[7] = (_Float16)b.w;
    return r;
}

// exp2: guarantee a single v_exp_f32 (HW computes 2^x)
#if __has_builtin(__builtin_amdgcn_exp2f)
#define EXP2(x) __builtin_amdgcn_exp2f(x)
#else
#define EXP2(x) exp2f(x)
#endif

// permlane32_swap: newA = {A_lo, B_lo}, newB = {A_hi, B_hi}.
static __device__ __forceinline__ void pl32swap(unsigned int& a, unsigned int& b) {
#if __has_builtin(__builtin_amdgcn_permlane32_swap)
    auto r = __builtin_amdgcn_permlane32_swap((int)a, (int)b, false, false);
    a = (unsigned int)r[0];
    b = (unsigned int)r[1];
#else
    const bool lh0 = ((threadIdx.x & 63) < 32);
    unsigned int xa = (unsigned int)__shfl_xor((int)a, 32);
    unsigned int xb = (unsigned int)__shfl_xor((int)b, 32);
    unsigned int na = lh0 ? a : xb;
    unsigned int nb = lh0 ? xa : b;
    a = na; b = nb;
#endif
}

// ---------------------------------------------------------------------------
// WORKSPACE LAYOUTS (fragment-major; unchanged from R12 — passed):
//   q_ws: [bh][s][64] f16, q pre-scaled by 0.1125*log2(e).
//   k_ws: [bh][T][h][lh][m32][8] f16  — wave reads frag h as one 1KB block.
//   v_ws: [bh][T][fg][lh][m32][8] f16 — same addressing structure.
// ---------------------------------------------------------------------------
#define QKST 520

__global__ __launch_bounds__(256)
void proj_kernel(const float* __restrict__ query, const float* __restrict__ key,
                 const float* __restrict__ value,
                 const float* __restrict__ Wq, const float* __restrict__ bq,
                 const float* __restrict__ Wk, const float* __restrict__ bk,
                 const float* __restrict__ Wv, const float* __restrict__ bv,
                 short* __restrict__ qws, short* __restrict__ kws,
                 short* __restrict__ vws)
{
    __shared__ __align__(16) short shbuf[16384];   // 32 KB, unioned per path

    const int tid  = threadIdx.x;
    const int wave = tid >> 6;
    const int lane = tid & 63;
    const int n    = lane & 15;
    const int quad = lane >> 4;
    const int kind = blockIdx.y;             // 0=q, 1=k, 2=v

    if (kind < 2) {
        short* tile = shbuf;                 // 16 x QKST = 16640 B
        const int r0   = blockIdx.x * 16;
        const int b    = r0 >> 11;
        const int s0   = r0 & 2047;
        // (1-dropout)/num_heads = 0.9/8 = 0.1125, times log2(e) for exp2 softmax
        const float QS = 0.16230319188537014f;

        const float* X    = kind ? key : query;
        const float* W    = kind ? Wk  : Wq;
        const float* bias = kind ? bk  : bq;
        short*       ows  = kind ? kws : qws;

        f16x8 af = load8_f32_f16(X + (r0 + n) * 32 + quad * 8);
        #pragma unroll
        for (int i = 0; i < 8; ++i) {
            const int c0 = wave * 128 + i * 16;
            f16x8 bfr = load8_f32_f16(W + (c0 + n) * 32 + quad * 8);
            f32x4 acc = {0.f, 0.f, 0.f, 0.f};
            acc = __builtin_amdgcn_mfma_f32_16x16x32_f16(af, bfr, acc, 0, 0, 0);
            const int c = c0 + n;
            const float bsf = bias[c];
            #pragma unroll
            for (int r = 0; r < 4; ++r) {
                float v = acc[r] + bsf;
                if (kind == 0) v *= QS;
                tile[(quad * 4 + r) * QKST + c] = f16bits(v);
            }
        }
        __syncthreads();

        #pragma unroll
        for (int k = 0; k < 4; ++k) {
            const int slot = k * 256 + tid;
            const int li   = slot & 7;          // d8 within head = h*2+lh
            const int chunk= slot >> 3;
            const int row  = chunk & 15;
            const int hd   = chunk >> 4;        // head 0..7
            uint4 vv = *(const uint4*)(tile + row * QKST + hd * 64 + li * 8);
            const int bh = b * 8 + hd;
            if (kind == 0) {
                *(uint4*)(ows + ((size_t)bh * S_ + s0 + row) * 64 + li * 8) = vv;
            } else {
                const int s = s0 + row;
                // k frag layout: bh*S*64 + T*2048 + li*256 + m32*8
                *(uint4*)(ows + (size_t)bh * (S_ * 64)
                              + (size_t)(s >> 5) * 2048 + li * 256 + (s & 31) * 8) = vv;
            }
        }
    } else {
        if (blockIdx.x >= 256) return;       // v path needs only 256 blocks
        short* vtile = shbuf;                // 2*256*32 shorts = 32768 B
        const int r0   = blockIdx.x * 64;
        const int b    = r0 >> 11;
        const int s0   = r0 & 2047;
        const int sub  = wave >> 1;
        const int sh   = (wave & 1) * 16;

        #pragma unroll
        for (int half = 0; half < 2; ++half) {
            const int cbh = half * 256;
            f16x8 bfr = load8_f32_f16(value + (r0 + sub * 32 + sh + n) * 32 + quad * 8);
            #pragma unroll
            for (int i = 0; i < 16; ++i) {
                const int c0 = cbh + i * 16;
                f16x8 af = load8_f32_f16(Wv + (c0 + n) * 32 + quad * 8);
                f32x4 acc = {0.f, 0.f, 0.f, 0.f};
                acc = __builtin_amdgcn_mfma_f32_16x16x32_f16(af, bfr, acc, 0, 0, 0);
                #pragma unroll
                for (int r = 0; r < 4; ++r) {
                    const int dc = c0 + quad * 4 + r;
                    float v = acc[r] + bv[dc];
                    vtile[(sub * 256 + (dc - cbh)) * 32 + sh + n] = f16bits(v);
                }
            }
            __syncthreads();

            #pragma unroll
            for (int k = 0; k < 8; ++k) {
                const int slot = k * 256 + tid;
                const int li   = slot & 3;          // k8 within tile (0..3)
                const int cl   = (slot >> 2) & 255;
                const int sb   = slot >> 10;
                const int c    = cbh + cl;
                const int bh   = b * 8 + (c >> 6);
                const int d    = c & 63;
                const int stile= (s0 >> 5) + sb;
                uint4 vv = *(const uint4*)(vtile + (sb * 256 + cl) * 32 + li * 8);
                // v frag layout: bh*S*64 + T*2048 + ((d>>5)*4+(li>>1)*2+(li&1))*256 + m32*8
                *(uint4*)(vws + (size_t)bh * (S_ * 64)
                              + (size_t)stile * 2048
                              + ((d >> 5) * 4 + (li >> 1) * 2 + (li & 1)) * 256
                              + (d & 31) * 8) = vv;
            }
            if (half == 0) __syncthreads();  // reuse vtile for second half
        }
    }
}

// ---------------------------------------------------------------------------
// Kernel 2: flash attention. R17 = EXACT REVERT TO R15 (measured best:
// flash 80.4 us; no-LDS frag-major streaming + A/B ping-pong + setprio).
// R10 lesson: fdot2 row-sums (+serial 2-cyc f16 dot chain) and the qg-braid
// (longer st[1] live range -> tighter regalloc, VGPR 112->100) both ADDED
// issue slots: 80.4 -> 85.6. Eighth confirmation that the per-tile
// instruction bill is the wall; substitutions/reorderings only add.
// Final ledger: occupancy hard-capped 2 waves/SIMD (R3/R7), barriers free
// (R4), latency free (R5), LDS free (R6), 2-state pipeline negative (R8),
// setprio +2.7% (R9), braid/fdot2 negative (R10). MFMA 37% + VALU 40% at
// the 2-wave interleave limit; memory an order below all ceilings.
// Per pre-commit: after this restore -> ROOFLINE.
// ---------------------------------------------------------------------------
#define OTS 36   // epilogue LDS row stride (f32) for one 32-wide d-tile

static __device__ __forceinline__ void flash_compute(
    const f16x8 (&kf)[4], const f16x8 (&va)[4],
    const f16x8 (&qb)[2][4], const f32x16& z16,
    f32x16 (&o)[2][2], float (&pl)[2])
{
    #pragma unroll
    for (int qg = 0; qg < 2; ++qg) {
        __builtin_amdgcn_s_setprio(1);
        f32x16 st = __builtin_amdgcn_mfma_f32_32x32x16_f16(kf[0], qb[qg][0], z16, 0, 0, 0);
        #pragma unroll
        for (int h = 1; h < 4; ++h)
            st = __builtin_amdgcn_mfma_f32_32x32x16_f16(kf[h], qb[qg][h], st, 0, 0, 0);
        __builtin_amdgcn_s_setprio(0);

        float p[16];
        #pragma unroll
        for (int r = 0; r < 16; ++r) p[r] = EXP2(st[r]);
        float s01 = (p[0]+p[1]) + (p[2]+p[3]);
        float s23 = (p[4]+p[5]) + (p[6]+p[7]);
        float s45 = (p[8]+p[9]) + (p[10]+p[11]);
        float s67 = (p[12]+p[13]) + (p[14]+p[15]);
        pl[qg] += (s01 + s23) + (s45 + s67);

        unsigned int pk[8];
        #pragma unroll
        for (int i = 0; i < 8; ++i)
            pk[i] = __builtin_bit_cast(unsigned int,
                      __builtin_amdgcn_cvt_pkrtz(p[2 * i], p[2 * i + 1]));
        pl32swap(pk[0], pk[2]);
        pl32swap(pk[1], pk[3]);
        pl32swap(pk[4], pk[6]);
        pl32swap(pk[5], pk[7]);

        i32x4 bi0, bi1;
        bi0[0] = (int)pk[0]; bi0[1] = (int)pk[1];
        bi0[2] = (int)pk[2]; bi0[3] = (int)pk[3];
        bi1[0] = (int)pk[4]; bi1[1] = (int)pk[5];
        bi1[2] = (int)pk[6]; bi1[3] = (int)pk[7];
        f16x8 bf0 = __builtin_bit_cast(f16x8, bi0);
        f16x8 bf1 = __builtin_bit_cast(f16x8, bi1);

        __builtin_amdgcn_s_setprio(1);
        #pragma unroll
        for (int t = 0; t < 2; ++t) {
            o[qg][t] = __builtin_amdgcn_mfma_f32_32x32x16_f16(va[t * 2 + 0], bf0, o[qg][t], 0, 0, 0);
            o[qg][t] = __builtin_amdgcn_mfma_f32_32x32x16_f16(va[t * 2 + 1], bf1, o[qg][t], 0, 0, 0);
        }
        __builtin_amdgcn_s_setprio(0);
    }
}

__global__ __launch_bounds__(256, 2)
void flash_kernel(const short* __restrict__ qws, const short* __restrict__ kws,
                  const short* __restrict__ vws, float* __restrict__ out)
{
    __shared__ __align__(16) float olds[4 * 32 * OTS];   // 18432 B (epilogue only)

    const int tid  = threadIdx.x;
    const int wave = tid >> 6;
    const int lane = tid & 63;
    const int m32  = lane & 31;
    const int lh   = lane >> 5;          // lane-half
    const int koff = lh * 8;
    const int bh   = blockIdx.x;                     // XCD = bh % 8
    const int q0   = blockIdx.y * 256 + wave * 64;   // 64 q-rows per wave

    const short* qbase = qws + (size_t)bh * S_ * D_;
    const short* kfb   = kws + (size_t)bh * (S_ * 64);   // frag-major tiles
    const short* vfb   = vws + (size_t)bh * (S_ * 64);
    const int loff = lh * 256 + m32 * 8;                 // lane part of frag addr

    // Q^T B-frags (held): qb[qg][h]: B[d=h*16+lh*8+j][q=m32]
    f16x8 qb[2][4];
    #pragma unroll
    for (int qg = 0; qg < 2; ++qg)
        #pragma unroll
        for (int h = 0; h < 4; ++h)
            qb[qg][h] = *(const f16x8*)(qbase + (q0 + qg * 32 + m32) * D_ + h * 16 + koff);

    f32x16 z16;
    #pragma unroll
    for (int r = 0; r < 16; ++r) z16[r] = 0.f;

    f32x16 o[2][2];      // [qg][d-tile] O^T accumulators
    float  pl[2] = {0.f, 0.f};
    #pragma unroll
    for (int qg = 0; qg < 2; ++qg)
        #pragma unroll
        for (int t = 0; t < 2; ++t)
            o[qg][t] = z16;

    // frag loads: 8 contiguous 1KB wave-loads per tile, direct from global
    #define LOADFRAGS(T, kf, va) do {                                        \
        const short* kp_ = kfb + (size_t)(T) * 2048 + loff;                  \
        const short* vp_ = vfb + (size_t)(T) * 2048 + loff;                  \
        kf[0] = *(const f16x8*)(kp_);                                        \
        kf[1] = *(const f16x8*)(kp_ + 512);                                  \
        kf[2] = *(const f16x8*)(kp_ + 1024);                                 \
        kf[3] = *(const f16x8*)(kp_ + 1536);                                 \
        va[0] = *(const f16x8*)(vp_);                                        \
        va[1] = *(const f16x8*)(vp_ + 512);                                  \
        va[2] = *(const f16x8*)(vp_ + 1024);                                 \
        va[3] = *(const f16x8*)(vp_ + 1536);                                 \
    } while (0)

    f16x8 kfA[4], vaA[4], kfB[4], vaB[4];
    LOADFRAGS(0, kfA, vaA);

    for (int it = 0; it < 64; it += 2) {
        LOADFRAGS(it + 1, kfB, vaB);             // it+1 <= 63 always
        flash_compute(kfA, vaA, qb, z16, o, pl);
        if (it + 2 < 64)
            LOADFRAGS(it + 2, kfA, vaA);
        flash_compute(kfB, vaB, qb, z16, o, pl);
    }
    #undef LOADFRAGS

    // epilogue: complete row sums across lane-halves, normalize, transpose
    // O^T -> O one 32-wide d-tile at a time through per-wave LDS (32x36 f32,
    // per-wave region — no cross-wave hazard, no barrier), coalesced stores.
    const int b = bh >> 3, h = bh & 7;
    float* ow = olds + wave * (32 * OTS);
    #pragma unroll
    for (int qg = 0; qg < 2; ++qg) {
        float rs = pl[qg] + __shfl_xor(pl[qg], 32);
        float rl = 1.0f / rs;
        #pragma unroll
        for (int t = 0; t < 2; ++t) {
            const f32x16& ot = o[qg][t];
            #pragma unroll
            for (int g = 0; g < 4; ++g) {
                f32x4 w;
                w[0] = ot[g * 4 + 0] * rl;
                w[1] = ot[g * 4 + 1] * rl;
                w[2] = ot[g * 4 + 2] * rl;
                w[3] = ot[g * 4 + 3] * rl;
                // element (q=m32, dcol=r+8g+4lh) of this 32-wide d-tile
                *(f32x4*)(ow + m32 * OTS + 8 * g + 4 * lh) = w;
            }
            #pragma unroll
            for (int c = 0; c < 4; ++c) {
                const int row = (lane >> 3) + 8 * c;       // q-row within 32-row group
                f32x4 v = *(const f32x4*)(ow + row * OTS + (lane & 7) * 4);
                const int sq = q0 + qg * 32 + row;
                *(f32x4*)(out + ((size_t)(b * S_ + sq)) * DPROJ_
                              + h * 64 + t * 32 + (lane & 7) * 4) = v;
            }
        }
    }
}

// ---------------------------------------------------------------------------
extern "C" void kernel_launch(void* const* d_in, const int* in_sizes, int n_in,
                              void* d_out, int out_size, void* d_ws, size_t ws_size,
                              hipStream_t stream)
{
    const float* query = (const float*)d_in[0];
    const float* key   = (const float*)d_in[1];
    const float* value = (const float*)d_in[2];
    // d_in[3] = mask (int32) -- only its shape feeds the reference; unused.
    const float* Wq = (const float*)d_in[4];
    const float* bq = (const float*)d_in[5];
    const float* Wk = (const float*)d_in[6];
    const float* bk = (const float*)d_in[7];
    const float* Wv = (const float*)d_in[8];
    const float* bv = (const float*)d_in[9];

    float* out = (float*)d_out;
    short* ws  = (short*)d_ws;
    const size_t TSZ = (size_t)BH_ * S_ * D_;
    short* qws = ws;
    short* kws = ws + TSZ;
    short* vws = ws + 2 * TSZ;

    proj_kernel<<<dim3((B_ * S_) / 16, 3), 256, 0, stream>>>(
        query, key, value, Wq, bq, Wk, bk, Wv, bv, qws, kws, vws);
    flash_kernel<<<dim3(BH_, S_ / 256), 256, 0, stream>>>(qws, kws, vws, out);
}